// Round 11
// baseline (140.849 us; speedup 1.0000x reference)
//
#include <hip/hip_runtime.h>

// Hierarchical softmax: B=4096, NHID=512, BR=32, DEPTH=3, V=32768.
// bucket g = lab>>5. node0=0 (step g>>5), node1=1+(g>>5) (step g&31),
// node2=33+g (step lab&31). out[b] = prod_k softmax(x_b @ W[node_k])[step_k]
//
// R11: same sort + node2-uniform groups of 8, wave k = level k. W stream is
// now a double-buffered global_load_lds DMA pipeline (16 chunks x 4 KB, 4x
// 1 KB DMAs each, explicit s_waitcnt vmcnt(4)/vmcnt(0)). Rationale: R9/R10
// proved the compiler never keeps register loads in flight (per-wave rate
// pinned at ~1.4 GB/s); global_load_lds has no dest VGPR so it CANNOT be
// serialized by the register scheduler (m97 evidence: ~44 B/cyc/CU).

#define NHID  512
#define BR    32
#define BATCH 4096
#define NBUCK 1024
#define SMAX  8
#define GMAX  1536

#define FMA4(A, xv, wv_) do { \
    (A).x = fmaf((xv), (wv_).x, (A).x); \
    (A).y = fmaf((xv), (wv_).y, (A).y); \
    (A).z = fmaf((xv), (wv_).z, (A).z); \
    (A).w = fmaf((xv), (wv_).w, (A).w); } while (0)

__device__ __forceinline__ void dma16(const float* g, float* l) {
    __builtin_amdgcn_global_load_lds(
        (const __attribute__((address_space(1))) void*)g,
        (__attribute__((address_space(3))) void*)l,
        16, 0, 0);
}
__device__ __forceinline__ void wait_vm4() {
    asm volatile("s_waitcnt vmcnt(4)" ::: "memory");
}
__device__ __forceinline__ void wait_vm0() {
    asm volatile("s_waitcnt vmcnt(0)" ::: "memory");
}

// ---------- single-block counting sort + ordered group descriptors ----------
__global__ __launch_bounds__(1024) void k_sort(const int* __restrict__ labels,
                                               int* __restrict__ order,
                                               int* __restrict__ ngroups,
                                               int* __restrict__ gdesc) {
    __shared__ int labs[BATCH];    // 16 KB
    __shared__ int hist[NBUCK];    // 4 KB (count -> cursor)
    __shared__ int wsum1[16];
    __shared__ int wsum2[16];
    const int t  = threadIdx.x;
    const int wv = t >> 6;
    const int ln = t & 63;

    hist[t] = 0;
    #pragma unroll
    for (int r = 0; r < BATCH / 1024; ++r)
        labs[t + 1024 * r] = labels[t + 1024 * r];
    __syncthreads();
    #pragma unroll
    for (int r = 0; r < BATCH / 1024; ++r)
        atomicAdd(&hist[labs[t + 1024 * r] >> 5], 1);
    __syncthreads();

    const int cnt  = hist[t];
    const int gcnt = (cnt + SMAX - 1) / SMAX;

    int s1 = cnt, s2 = gcnt;
    #pragma unroll
    for (int d = 1; d < 64; d <<= 1) {
        int u1 = __shfl_up(s1, d);
        int u2 = __shfl_up(s2, d);
        if (ln >= d) { s1 += u1; s2 += u2; }
    }
    if (ln == 63) { wsum1[wv] = s1; wsum2[wv] = s2; }
    __syncthreads();
    if (t < 16) {
        int a = wsum1[t], b = wsum2[t];
        #pragma unroll
        for (int d = 1; d < 16; d <<= 1) {
            int ua = __shfl_up(a, d, 16);
            int ub = __shfl_up(b, d, 16);
            if (t >= d) { a += ua; b += ub; }
        }
        wsum1[t] = a; wsum2[t] = b;
        if (t == 15) *ngroups = b;
    }
    __syncthreads();
    const int base1 = (wv > 0) ? wsum1[wv - 1] : 0;
    const int base2 = (wv > 0) ? wsum2[wv - 1] : 0;
    const int off  = base1 + s1 - cnt;
    const int goff = base2 + s2 - gcnt;
    hist[t] = off;
    __syncthreads();

    for (int j = 0; j < gcnt; ++j)
        gdesc[goff + j] = (off + j * SMAX)
                        | (min(SMAX, cnt - j * SMAX) << 12)
                        | (t << 16);

    #pragma unroll
    for (int r = 0; r < BATCH / 1024; ++r) {
        int j = t + 1024 * r;
        int pos = atomicAdd(&hist[labs[j] >> 5], 1);
        order[pos] = j;
    }
}

// ---------- compute: one block per group of 8, DMA-pipelined W ----------
__global__ __launch_bounds__(192) void hsm_dma(
    const float* __restrict__ inputs,
    const int* __restrict__ labels,
    const float* __restrict__ W,
    const int* __restrict__ order,
    const int* __restrict__ ngroups,
    const int* __restrict__ gdesc,
    float* __restrict__ out)
{
    __shared__ float xsT[NHID * SMAX];     // 16 KB, xsT[h][s0..7]
    __shared__ float wlds[3 * 2 * 1024];   // 24 KB: per-wave 2 x 4 KB buffers
    __shared__ float pk[3][SMAX];
    __shared__ int   sids[SMAX];
    __shared__ int   slab[SMAX];

    const int gid = blockIdx.x;
    if (gid >= *ngroups) return;
    const int d     = gdesc[gid];
    const int start = d & 0xFFF;
    const int m     = (d >> 12) & 0xF;
    const int g     = d >> 16;
    const int tid   = threadIdx.x;

    if (tid < SMAX) {
        int sid = (tid < m) ? order[start + tid] : -1;
        sids[tid] = sid;
        slab[tid] = (sid >= 0) ? labels[sid] : 0;
    }
    __syncthreads();

    // ---- stage xsT[h][0..7] (32 B rows), zero-pad unused slots ----
    for (int h = tid; h < NHID; h += 192) {
        float v[SMAX];
        #pragma unroll
        for (int s = 0; s < SMAX; ++s) {
            int id = sids[s];
            v[s] = (id >= 0) ? inputs[(size_t)id * NHID + h] : 0.0f;
        }
        float4* dst = (float4*)&xsT[h * SMAX];
        dst[0] = make_float4(v[0], v[1], v[2], v[3]);
        dst[1] = make_float4(v[4], v[5], v[6], v[7]);
    }
    __syncthreads();   // drains all vmcnt/lgkmcnt -> clean slate for DMA count

    const int wv   = tid >> 6;    // wave = tree level
    const int lane = tid & 63;
    const int colg = lane & 7;    // float4 column group
    const int hsel = lane >> 3;   // h strip

    const int node = (wv == 0) ? 0 : (wv == 1) ? 1 + (g >> 5) : 33 + g;
    const int step01 = (wv == 0) ? (g >> 5) : (g & 31);

    const float* wg = W + (size_t)node * (NHID * BR);   // 16384 floats
    float* wb = &wlds[wv * 2048];                        // my 2 x 1024-float buffers

    float4 acc[SMAX];
    #pragma unroll
    for (int s = 0; s < SMAX; ++s) acc[s] = make_float4(0, 0, 0, 0);

    // prologue: DMA chunk 0 (32 rows = 4 KB = 4 x 1 KB)
    #pragma unroll
    for (int j = 0; j < 4; ++j)
        dma16(wg + j * 256 + lane * 4, wb + j * 256);

    // 16-chunk double-buffered pipeline
    #pragma unroll 4
    for (int c = 0; c < 16; ++c) {
        const float* cur = wb + (c & 1) * 1024;
        float* nxt = wb + ((c + 1) & 1) * 1024;
        if (c < 15) {
            const float* gsrc = wg + (c + 1) * 1024;
            #pragma unroll
            for (int j = 0; j < 4; ++j)
                dma16(gsrc + j * 256 + lane * 4, nxt + j * 256);
            wait_vm4();   // chunk c's 4 DMAs done; chunk c+1 in flight
        } else {
            wait_vm0();
        }
        // compute chunk c: 32 rows; lane handles rows hsel + 8t
        #pragma unroll
        for (int t = 0; t < 4; ++t) {
            const int rr = hsel + 8 * t;
            float4 w = *(const float4*)&cur[rr * 32 + colg * 4];
            const float4* xr = (const float4*)&xsT[(c * 32 + rr) * SMAX];
            float4 xa = xr[0];
            float4 xb = xr[1];
            FMA4(acc[0], xa.x, w); FMA4(acc[1], xa.y, w);
            FMA4(acc[2], xa.z, w); FMA4(acc[3], xa.w, w);
            FMA4(acc[4], xb.x, w); FMA4(acc[5], xb.y, w);
            FMA4(acc[6], xb.z, w); FMA4(acc[7], xb.w, w);
        }
    }

    // butterfly-reduce over hsel (masks 8,16,32): all lanes get full sums
    #pragma unroll
    for (int s = 0; s < SMAX; ++s) {
        #pragma unroll
        for (int mm = 8; mm <= 32; mm <<= 1) {
            acc[s].x += __shfl_xor(acc[s].x, mm);
            acc[s].y += __shfl_xor(acc[s].y, mm);
            acc[s].z += __shfl_xor(acc[s].z, mm);
            acc[s].w += __shfl_xor(acc[s].w, mm);
        }
    }

    // per-sample softmax over 32 logits (8 colg lanes x 4 comps)
    #pragma unroll
    for (int s = 0; s < SMAX; ++s) {
        float4 a = acc[s];
        float mx = fmaxf(fmaxf(a.x, a.y), fmaxf(a.z, a.w));
        #pragma unroll
        for (int mm = 1; mm <= 4; mm <<= 1) mx = fmaxf(mx, __shfl_xor(mx, mm));
        float es = expf(a.x - mx) + expf(a.y - mx) + expf(a.z - mx) + expf(a.w - mx);
        #pragma unroll
        for (int mm = 1; mm <= 4; mm <<= 1) es += __shfl_xor(es, mm);

        int step = (wv == 2) ? (slab[s] & 31) : step01;
        int e = step & 3;
        float v = (e == 0) ? a.x : (e == 1) ? a.y : (e == 2) ? a.z : a.w;
        float sl = __shfl(v, step >> 2);
        float p = expf(sl - mx) / es;
        if (lane == 0) pk[wv][s] = p;
    }
    __syncthreads();

    if (tid < SMAX && sids[tid] >= 0)
        out[sids[tid]] = pk[0][tid] * pk[1][tid] * pk[2][tid];
}

extern "C" void kernel_launch(void* const* d_in, const int* in_sizes, int n_in,
                              void* d_out, int out_size, void* d_ws, size_t ws_size,
                              hipStream_t stream)
{
    const float* inputs = (const float*)d_in[0];
    const int*   labels = (const int*)d_in[1];
    const float* W      = (const float*)d_in[2];
    float* out = (float*)d_out;

    char* ws = (char*)d_ws;
    int* order   = (int*)ws;                  // 16 KB
    int* ngroups = (int*)(ws + 16384);        // 4 B (padded to 128)
    int* gdesc   = (int*)(ws + 16384 + 128);  // 6 KB

    k_sort <<<dim3(1),    dim3(1024), 0, stream>>>(labels, order, ngroups, gdesc);
    hsm_dma<<<dim3(GMAX), dim3(192),  0, stream>>>(inputs, labels, W, order,
                                                   ngroups, gdesc, out);
}

// Round 12
// 125.975 us; speedup vs baseline: 1.1181x; 1.1181x over previous
//
#include <hip/hip_runtime.h>

// Hierarchical softmax: B=4096, NHID=512, BR=32, DEPTH=3, V=32768.
// bucket g = lab>>5. node0=0 (step g>>5), node1=1+(g>>5) (step g&31),
// node2=33+g (step lab&31). out[b] = prod_k softmax(x_b @ W[node_k])[step_k]
//
// R12: sort -> ~1035 node2-uniform groups of 8 (as R8). Compute block is now
// 768 threads = 12 waves = (level k 0..2) x (K-quarter q 0..3): each wave
// streams only 16 KB of W (16 x 1 KB coalesced loads, barrier-free).
// Cross-round model: kernel time == per-wave serial stream time (~650 cyc
// per 1 KB load, 1 outstanding) bounded below by the ~25 B/cyc/CU aggregate
// wall. Shortening streams 64->16 KB and lifting waves/CU 8->24 attacks both.

#define NHID  512
#define BR    32
#define BATCH 4096
#define NBUCK 1024
#define SMAX  8
#define GMAX  1536

#define FMA4(A, xv, wv_) do { \
    (A).x = fmaf((xv), (wv_).x, (A).x); \
    (A).y = fmaf((xv), (wv_).y, (A).y); \
    (A).z = fmaf((xv), (wv_).z, (A).z); \
    (A).w = fmaf((xv), (wv_).w, (A).w); } while (0)

// ---------- single-block counting sort + ordered group descriptors ----------
__global__ __launch_bounds__(1024) void k_sort(const int* __restrict__ labels,
                                               int* __restrict__ order,
                                               int* __restrict__ ngroups,
                                               int* __restrict__ gdesc) {
    __shared__ int labs[BATCH];    // 16 KB
    __shared__ int hist[NBUCK];    // 4 KB (count -> cursor)
    __shared__ int wsum1[16];
    __shared__ int wsum2[16];
    const int t  = threadIdx.x;
    const int wv = t >> 6;
    const int ln = t & 63;

    hist[t] = 0;
    #pragma unroll
    for (int r = 0; r < BATCH / 1024; ++r)
        labs[t + 1024 * r] = labels[t + 1024 * r];
    __syncthreads();
    #pragma unroll
    for (int r = 0; r < BATCH / 1024; ++r)
        atomicAdd(&hist[labs[t + 1024 * r] >> 5], 1);
    __syncthreads();

    const int cnt  = hist[t];
    const int gcnt = (cnt + SMAX - 1) / SMAX;

    int s1 = cnt, s2 = gcnt;
    #pragma unroll
    for (int d = 1; d < 64; d <<= 1) {
        int u1 = __shfl_up(s1, d);
        int u2 = __shfl_up(s2, d);
        if (ln >= d) { s1 += u1; s2 += u2; }
    }
    if (ln == 63) { wsum1[wv] = s1; wsum2[wv] = s2; }
    __syncthreads();
    if (t < 16) {
        int a = wsum1[t], b = wsum2[t];
        #pragma unroll
        for (int d = 1; d < 16; d <<= 1) {
            int ua = __shfl_up(a, d, 16);
            int ub = __shfl_up(b, d, 16);
            if (t >= d) { a += ua; b += ub; }
        }
        wsum1[t] = a; wsum2[t] = b;
        if (t == 15) *ngroups = b;
    }
    __syncthreads();
    const int base1 = (wv > 0) ? wsum1[wv - 1] : 0;
    const int base2 = (wv > 0) ? wsum2[wv - 1] : 0;
    const int off  = base1 + s1 - cnt;
    const int goff = base2 + s2 - gcnt;
    hist[t] = off;
    __syncthreads();

    for (int j = 0; j < gcnt; ++j)
        gdesc[goff + j] = (off + j * SMAX)
                        | (min(SMAX, cnt - j * SMAX) << 12)
                        | (t << 16);

    #pragma unroll
    for (int r = 0; r < BATCH / 1024; ++r) {
        int j = t + 1024 * r;
        int pos = atomicAdd(&hist[labs[j] >> 5], 1);
        order[pos] = j;
    }
}

// ---------- compute: 12 waves = (level, K-quarter); 16 KB stream per wave ----
__global__ __launch_bounds__(768, 6) void hsm_w12(
    const float* __restrict__ inputs,
    const int* __restrict__ labels,
    const float* __restrict__ W,
    const int* __restrict__ order,
    const int* __restrict__ ngroups,
    const int* __restrict__ gdesc,
    float* __restrict__ out)
{
    __shared__ float xsT[NHID * SMAX];            // 16 KB, xsT[h][s0..7]
    __shared__ float partial[3 * 4 * SMAX * BR];  // 12 KB [k][q][s][col]
    __shared__ float pk[3][SMAX];
    __shared__ int   sids[SMAX];
    __shared__ int   slab[SMAX];

    const int gid = blockIdx.x;
    if (gid >= *ngroups) return;
    const int d     = gdesc[gid];
    const int start = d & 0xFFF;
    const int m     = (d >> 12) & 0xF;
    const int g     = d >> 16;
    const int tid   = threadIdx.x;

    if (tid < SMAX) {
        int sid = (tid < m) ? order[start + tid] : -1;
        sids[tid] = sid;
        slab[tid] = (sid >= 0) ? labels[sid] : 0;
    }
    __syncthreads();

    // ---- stage xsT[h][0..7] (32 B rows), zero-pad unused slots ----
    if (tid < NHID) {
        const int h = tid;
        float v[SMAX];
        #pragma unroll
        for (int s = 0; s < SMAX; ++s) {
            int id = sids[s];
            v[s] = (id >= 0) ? inputs[(size_t)id * NHID + h] : 0.0f;
        }
        float4* dst = (float4*)&xsT[h * SMAX];
        dst[0] = make_float4(v[0], v[1], v[2], v[3]);
        dst[1] = make_float4(v[4], v[5], v[6], v[7]);
    }
    __syncthreads();

    const int w    = tid >> 6;    // wave 0..11
    const int lane = tid & 63;
    const int k    = w >> 2;      // level 0..2
    const int q    = w & 3;       // K-quarter 0..3
    const int colg = lane & 7;    // float4 column group
    const int hsel = lane >> 3;   // h strip: row = 128q + 8i + hsel

    const int node = (k == 0) ? 0 : (k == 1) ? 1 + (g >> 5) : 33 + g;

    const float4* wp = (const float4*)(W + (size_t)node * (NHID * BR))
                       + q * 1024 + hsel * 8 + colg;
    const float4* xp = (const float4*)xsT + (128 * q + hsel) * 2;

    float4 acc[SMAX];
    #pragma unroll
    for (int s = 0; s < SMAX; ++s) acc[s] = make_float4(0, 0, 0, 0);

    // 16 KB barrier-free coalesced stream (16 x 1 KB/wave loads)
    #pragma unroll
    for (int i = 0; i < 16; ++i) {
        float4 w4 = wp[i * 64];
        float4 xa = xp[i * 16];
        float4 xb = xp[i * 16 + 1];
        FMA4(acc[0], xa.x, w4); FMA4(acc[1], xa.y, w4);
        FMA4(acc[2], xa.z, w4); FMA4(acc[3], xa.w, w4);
        FMA4(acc[4], xb.x, w4); FMA4(acc[5], xb.y, w4);
        FMA4(acc[6], xb.z, w4); FMA4(acc[7], xb.w, w4);
    }

    // butterfly-reduce over hsel (masks 8,16,32): every lane completes its colg
    #pragma unroll
    for (int s = 0; s < SMAX; ++s) {
        #pragma unroll
        for (int mm = 8; mm <= 32; mm <<= 1) {
            acc[s].x += __shfl_xor(acc[s].x, mm);
            acc[s].y += __shfl_xor(acc[s].y, mm);
            acc[s].z += __shfl_xor(acc[s].z, mm);
            acc[s].w += __shfl_xor(acc[s].w, mm);
        }
    }
    // lanes 0..7 (colg == lane) write quarter-partials
    if (lane < 8) {
        #pragma unroll
        for (int s = 0; s < SMAX; ++s)
            *(float4*)&partial[((k * 4 + q) * SMAX + s) * BR + lane * 4] = acc[s];
    }
    __syncthreads();

    // ---- epilogue: 768 threads = (k, s, col); softmax within 32-thread rows --
    {
        const int kk  = tid >> 8;
        const int s   = (tid >> 5) & 7;
        const int col = tid & 31;
        float l = 0.0f;
        #pragma unroll
        for (int qq = 0; qq < 4; ++qq)
            l += partial[((kk * 4 + qq) * SMAX + s) * BR + col];
        float mx = l;
        #pragma unroll
        for (int mm = 1; mm <= 16; mm <<= 1)
            mx = fmaxf(mx, __shfl_xor(mx, mm, 32));
        float e  = expf(l - mx);
        float es = e;
        #pragma unroll
        for (int mm = 1; mm <= 16; mm <<= 1)
            es += __shfl_xor(es, mm, 32);
        int step = (kk == 0) ? (g >> 5)
                 : (kk == 1) ? (g & 31)
                             : (slab[s] & 31);
        if (col == step) pk[kk][s] = e / es;
    }
    __syncthreads();

    if (tid < SMAX && sids[tid] >= 0)
        out[sids[tid]] = pk[0][tid] * pk[1][tid] * pk[2][tid];
}

extern "C" void kernel_launch(void* const* d_in, const int* in_sizes, int n_in,
                              void* d_out, int out_size, void* d_ws, size_t ws_size,
                              hipStream_t stream)
{
    const float* inputs = (const float*)d_in[0];
    const int*   labels = (const int*)d_in[1];
    const float* W      = (const float*)d_in[2];
    float* out = (float*)d_out;

    char* ws = (char*)d_ws;
    int* order   = (int*)ws;                  // 16 KB
    int* ngroups = (int*)(ws + 16384);        // 4 B (padded to 128)
    int* gdesc   = (int*)(ws + 16384 + 128);  // 6 KB

    k_sort <<<dim3(1),    dim3(1024), 0, stream>>>(labels, order, ngroups, gdesc);
    hsm_w12<<<dim3(GMAX), dim3(768),  0, stream>>>(inputs, labels, W, order,
                                                   ngroups, gdesc, out);
}